// Round 1
// baseline (437.288 us; speedup 1.0000x reference)
//
#include <hip/hip_runtime.h>
#include <hip/hip_bf16.h>

// Problem constants (B=8, L=1025, E=384, H=6, D=64, WIN=33, PAD=16)
constexpr int Bc = 8;
constexpr int Lc = 1025;
constexpr int Ec = 384;
constexpr int Hc = 6;
constexpr int Dc = 64;
constexpr int MT = Bc * Lc;          // 8200 rows
constexpr int BHLD = Bc * Hc * Lc * Dc;  // 3,148,800 elems per tensor
constexpr float SCALE = 0.125f;      // 1/sqrt(64)

// ---------------------------------------------------------------------------
// Kernel 1: fused QKV projection.  C[m, n] = x[m,:] @ W[:, c] + b[c]
// n in [0,1152): which = n/384 selects Wq/Wk/Wv.  Output written directly in
// (B,H,L,D) layout: qkv[which*BHLD + ((b*H+h)*L + l)*D + d].
// 64x64 tile, 256 threads, 4x4 micro-tile, K-tiles of 16.
// ---------------------------------------------------------------------------
__global__ __launch_bounds__(256) void qkv_proj_kernel(
    const float* __restrict__ x,
    const float* __restrict__ Wq, const float* __restrict__ bq,
    const float* __restrict__ Wk, const float* __restrict__ bk,
    const float* __restrict__ Wv, const float* __restrict__ bv,
    float* __restrict__ qkv)
{
    __shared__ float As[64][17];   // [m][k], +1 pad
    __shared__ float Bs[16][65];   // [k][n], +1 pad

    const int tid = threadIdx.x;
    const int tx = tid & 15, ty = tid >> 4;
    const int m0 = blockIdx.x * 64;
    const int n0 = blockIdx.y * 64;
    const int which = n0 / Ec;            // 0:Q 1:K 2:V (uniform per block)
    const int c0 = n0 - which * Ec;       // multiple of 64
    const float* W    = (which == 0) ? Wq : (which == 1) ? Wk : Wv;
    const float* bias = (which == 0) ? bq : (which == 1) ? bk : bv;

    float acc[4][4] = {};

    for (int kt = 0; kt < Ec; kt += 16) {
#pragma unroll
        for (int i = 0; i < 4; i++) {           // A tile: 64x16
            int idx = tid + i * 256;
            int r = idx >> 4, c = idx & 15;
            int m = m0 + r;
            As[r][c] = (m < MT) ? x[(size_t)m * Ec + kt + c] : 0.f;
        }
#pragma unroll
        for (int i = 0; i < 4; i++) {           // B tile: 16x64
            int idx = tid + i * 256;
            int r = idx >> 6, c = idx & 63;
            Bs[r][c] = W[(size_t)(kt + r) * Ec + c0 + c];
        }
        __syncthreads();
#pragma unroll
        for (int kk = 0; kk < 16; kk++) {
            float a[4], b[4];
#pragma unroll
            for (int i = 0; i < 4; i++) a[i] = As[ty * 4 + i][kk];
#pragma unroll
            for (int j = 0; j < 4; j++) b[j] = Bs[kk][tx * 4 + j];
#pragma unroll
            for (int i = 0; i < 4; i++)
#pragma unroll
                for (int j = 0; j < 4; j++) acc[i][j] += a[i] * b[j];
        }
        __syncthreads();
    }

    const int h = c0 / 64;                // uniform per block
    float* outp = qkv + (size_t)which * BHLD;
#pragma unroll
    for (int i = 0; i < 4; i++) {
        int m = m0 + ty * 4 + i;
        if (m >= MT) break;
        int b_ = m / Lc, l = m - b_ * Lc;
        size_t base = ((size_t)(b_ * Hc + h) * Lc + l) * Dc;
#pragma unroll
        for (int j = 0; j < 4; j++) {
            int d = tx * 4 + j;
            outp[base + d] = acc[i][j] + bias[c0 + d];
        }
    }
}

// ---------------------------------------------------------------------------
// Kernel 2: CLS-token attention.  One block per (b,h); softmax over all 1025
// keys, weighted V sum -> attn row l=0.
// ---------------------------------------------------------------------------
__global__ __launch_bounds__(256) void cls_attn_kernel(
    const float* __restrict__ qkv, float* __restrict__ attn)
{
    const int bh = blockIdx.x;  // 0..47
    const float* Q = qkv + (size_t)bh * Lc * Dc;
    const float* K = qkv + (size_t)BHLD + (size_t)bh * Lc * Dc;
    const float* V = qkv + 2 * (size_t)BHLD + (size_t)bh * Lc * Dc;

    __shared__ float qs[64];
    __shared__ float sc[Lc];
    __shared__ float red[256];

    const int tid = threadIdx.x;
    if (tid < 64) qs[tid] = Q[tid];
    __syncthreads();

    float lmax = -1e30f;
    for (int k = tid; k < Lc; k += 256) {
        float s = 0.f;
        const float* kp = K + (size_t)k * Dc;
        for (int d = 0; d < Dc; d++) s += qs[d] * kp[d];
        s *= SCALE;
        sc[k] = s;
        lmax = fmaxf(lmax, s);
    }
    red[tid] = lmax; __syncthreads();
    for (int off = 128; off > 0; off >>= 1) {
        if (tid < off) red[tid] = fmaxf(red[tid], red[tid + off]);
        __syncthreads();
    }
    const float m = red[0];
    __syncthreads();

    float lsum = 0.f;
    for (int k = tid; k < Lc; k += 256) {
        float p = __expf(sc[k] - m);
        sc[k] = p;
        lsum += p;
    }
    red[tid] = lsum; __syncthreads();
    for (int off = 128; off > 0; off >>= 1) {
        if (tid < off) red[tid] += red[tid + off];
        __syncthreads();
    }
    const float inv = 1.f / red[0];
    __syncthreads();

    // PV: thread owns dim d = tid&63, k-slice = tid>>6
    const int d = tid & 63, slice = tid >> 6;
    float acc = 0.f;
    for (int k = slice; k < Lc; k += 4) acc += sc[k] * V[(size_t)k * Dc + d];
    red[tid] = acc; __syncthreads();
    if (tid < 64) {
        float o = (red[tid] + red[tid + 64] + red[tid + 128] + red[tid + 192]) * inv;
        attn[(size_t)bh * Lc * Dc + tid] = o;   // l = 0
    }
}

// ---------------------------------------------------------------------------
// Kernel 3: windowed attention for queries l=1..1024.
// Block = 64 consecutive queries of one (b,h).  Window slots w=0..32 map to
// key pos l+w-16 (valid iff 1<=pos<=1024); slot w=33 is the CLS key (pos 0).
// LDS: K/V window (97 pos) + Q tile, all padded to 65 floats/row.
// 4 lanes per query; softmax reduce via shfl_xor(1),(2).
// ---------------------------------------------------------------------------
__global__ __launch_bounds__(256) void win_attn_kernel(
    const float* __restrict__ qkv, float* __restrict__ attn)
{
    const int t = blockIdx.x;    // 0..15
    const int bh = blockIdx.y;   // 0..47
    const int l0 = 1 + t * 64;
    const float* Q = qkv + (size_t)bh * Lc * Dc;
    const float* K = qkv + (size_t)BHLD + (size_t)bh * Lc * Dc;
    const float* V = qkv + 2 * (size_t)BHLD + (size_t)bh * Lc * Dc;

    __shared__ float Kw[97][65];
    __shared__ float Vw[97][65];
    __shared__ float Qs[64][65];
    __shared__ float P[64][36];

    const int tid = threadIdx.x;
    for (int idx = tid; idx < 97 * 64; idx += 256) {
        int j = idx >> 6, d = idx & 63;
        int p = (j < 96) ? (l0 - 16 + j) : 0;
        bool valid = (j == 96) || (p >= 1 && p <= 1024);
        Kw[j][d] = valid ? K[(size_t)p * Dc + d] : 0.f;
        Vw[j][d] = valid ? V[(size_t)p * Dc + d] : 0.f;
    }
    for (int idx = tid; idx < 64 * 64; idx += 256) {
        int q = idx >> 6, d = idx & 63;
        Qs[q][d] = Q[(size_t)(l0 + q) * Dc + d];
    }
    __syncthreads();

    const int q = tid >> 2, sub = tid & 3;
    const int l = l0 + q;

    float svals[9];
    float lmax = -1e30f;
    int nw = 0;
    for (int w = sub; w < 34; w += 4) {
        int j = (w < 33) ? (q + w) : 96;
        float s = 0.f;
        for (int d = 0; d < Dc; d++) s += Qs[q][d] * Kw[j][d];
        s *= SCALE;
        bool valid = (w == 33) || ((l + w - 16 >= 1) && (l + w - 16 <= 1024));
        if (!valid) s = -1e30f;
        svals[nw++] = s;
        lmax = fmaxf(lmax, s);
    }
    lmax = fmaxf(lmax, __shfl_xor(lmax, 1));
    lmax = fmaxf(lmax, __shfl_xor(lmax, 2));

    float lsum = 0.f;
    nw = 0;
    for (int w = sub; w < 34; w += 4) {
        float p = __expf(svals[nw++] - lmax);
        P[q][w] = p;
        lsum += p;
    }
    lsum += __shfl_xor(lsum, 1);
    lsum += __shfl_xor(lsum, 2);
    const float inv = 1.f / lsum;
    __syncthreads();   // P visible to all lanes (same wave, but keep it simple)

    // PV: each sub-lane owns 16 dims
    float o[16] = {};
    for (int w = 0; w < 34; w++) {
        int j = (w < 33) ? (q + w) : 96;
        float p = P[q][w];
#pragma unroll
        for (int dd = 0; dd < 16; dd++) o[dd] += p * Vw[j][sub * 16 + dd];
    }
    size_t base = ((size_t)bh * Lc + l) * Dc + sub * 16;
#pragma unroll
    for (int dd = 0; dd < 16; dd++) attn[base + dd] = o[dd] * inv;
}

// ---------------------------------------------------------------------------
// Kernel 4: output projection.  out[m, n] = attn_rows[m,:] @ Wo[:, n] + bo[n]
// A is gathered from (B,H,L,D) layout: e = h*64+d.
// ---------------------------------------------------------------------------
__global__ __launch_bounds__(256) void out_proj_kernel(
    const float* __restrict__ attn, const float* __restrict__ Wo,
    const float* __restrict__ bo, float* __restrict__ out)
{
    __shared__ float As[64][17];
    __shared__ float Bs[16][65];

    const int tid = threadIdx.x;
    const int tx = tid & 15, ty = tid >> 4;
    const int m0 = blockIdx.x * 64;
    const int n0 = blockIdx.y * 64;

    float acc[4][4] = {};

    for (int kt = 0; kt < Ec; kt += 16) {
#pragma unroll
        for (int i = 0; i < 4; i++) {
            int idx = tid + i * 256;
            int r = idx >> 4, c = idx & 15;
            int m = m0 + r;
            float v = 0.f;
            if (m < MT) {
                int e = kt + c;
                int b_ = m / Lc, l = m - b_ * Lc;
                int h = e >> 6, d = e & 63;
                v = attn[((size_t)(b_ * Hc + h) * Lc + l) * Dc + d];
            }
            As[r][c] = v;
        }
#pragma unroll
        for (int i = 0; i < 4; i++) {
            int idx = tid + i * 256;
            int r = idx >> 6, c = idx & 63;
            Bs[r][c] = Wo[(size_t)(kt + r) * Ec + n0 + c];
        }
        __syncthreads();
#pragma unroll
        for (int kk = 0; kk < 16; kk++) {
            float a[4], b[4];
#pragma unroll
            for (int i = 0; i < 4; i++) a[i] = As[ty * 4 + i][kk];
#pragma unroll
            for (int j = 0; j < 4; j++) b[j] = Bs[kk][tx * 4 + j];
#pragma unroll
            for (int i = 0; i < 4; i++)
#pragma unroll
                for (int j = 0; j < 4; j++) acc[i][j] += a[i] * b[j];
        }
        __syncthreads();
    }

#pragma unroll
    for (int i = 0; i < 4; i++) {
        int m = m0 + ty * 4 + i;
        if (m >= MT) break;
#pragma unroll
        for (int j = 0; j < 4; j++) {
            int n = n0 + tx * 4 + j;
            out[(size_t)m * Ec + n] = acc[i][j] + bo[n];
        }
    }
}

// ---------------------------------------------------------------------------
extern "C" void kernel_launch(void* const* d_in, const int* in_sizes, int n_in,
                              void* d_out, int out_size, void* d_ws, size_t ws_size,
                              hipStream_t stream)
{
    const float* x  = (const float*)d_in[0];
    const float* Wq = (const float*)d_in[1];
    const float* bq = (const float*)d_in[2];
    const float* Wk = (const float*)d_in[3];
    const float* bk = (const float*)d_in[4];
    const float* Wv = (const float*)d_in[5];
    const float* bv = (const float*)d_in[6];
    const float* Wo = (const float*)d_in[7];
    const float* bo = (const float*)d_in[8];
    float* out = (float*)d_out;

    // Workspace: qkv (3*BHLD) + attn (BHLD) floats = 50.4 MB
    float* qkv  = (float*)d_ws;
    float* attn = qkv + 3 * (size_t)BHLD;

    dim3 g1((MT + 63) / 64, (3 * Ec) / 64);   // 129 x 18
    qkv_proj_kernel<<<g1, 256, 0, stream>>>(x, Wq, bq, Wk, bk, Wv, bv, qkv);

    cls_attn_kernel<<<Bc * Hc, 256, 0, stream>>>(qkv, attn);

    win_attn_kernel<<<dim3(16, Bc * Hc), 256, 0, stream>>>(qkv, attn);

    dim3 g4((MT + 63) / 64, Ec / 64);         // 129 x 6
    out_proj_kernel<<<g4, 256, 0, stream>>>(attn, Wo, bo, out);
}

// Round 2
// 228.711 us; speedup vs baseline: 1.9120x; 1.9120x over previous
//
#include <hip/hip_runtime.h>
#include <hip/hip_bf16.h>

typedef unsigned short ushort_t;
typedef __attribute__((ext_vector_type(8))) short short8;
typedef __attribute__((ext_vector_type(4))) float f32x4;

// Problem constants (B=8, L=1025, E=384, H=6, D=64, WIN=33, PAD=16)
constexpr int Bc = 8;
constexpr int Lc = 1025;
constexpr int Ec = 384;
constexpr int Hc = 6;
constexpr int Dc = 64;
constexpr int MT = Bc * Lc;              // 8200 rows
constexpr int BHLD = Bc * Hc * Lc * Dc;  // 3,148,800 elems per tensor
constexpr float SCALE = 0.125f;          // 1/sqrt(64)

__device__ __forceinline__ float bf2f(ushort_t u) {
    union { unsigned int u; float f; } v; v.u = ((unsigned int)u) << 16; return v.f;
}
__device__ __forceinline__ ushort_t f2bf(float f) {
    union { float f; unsigned int u; } v; v.f = f;
    unsigned int r = v.u + 0x7FFFu + ((v.u >> 16) & 1u);
    return (ushort_t)(r >> 16);
}

// global -> LDS direct copy, 16 B per lane. LDS dest must be wave-uniform base
// (HW writes base + lane*16); global src is per-lane.
#define GLOAD_LDS16(gp, lp)                                                          \
    __builtin_amdgcn_global_load_lds(                                                \
        (const __attribute__((address_space(1))) unsigned int*)(gp),                 \
        (__attribute__((address_space(3))) unsigned int*)(lp), 16, 0, 0)

// ---------------------------------------------------------------------------
// Cast x (fp32) -> xb (bf16).  MT*Ec = 3,148,800 = 4 * 787,200 elems.
// ---------------------------------------------------------------------------
__global__ __launch_bounds__(256) void cast_x_kernel(
    const float* __restrict__ x, ushort_t* __restrict__ xb)
{
    int i = blockIdx.x * 256 + threadIdx.x;   // grid sized exactly: 3075 blocks
    float4 v = ((const float4*)x)[i];
    ushort4 o;
    o.x = f2bf(v.x); o.y = f2bf(v.y); o.z = f2bf(v.z); o.w = f2bf(v.w);
    ((ushort4*)xb)[i] = o;
}

// ---------------------------------------------------------------------------
// Transpose+cast the four weight matrices: Wt[z][n][k] = W_z[k][n] in bf16.
// z: 0=Wq 1=Wk 2=Wv 3=Wo.  32x32 LDS tile, 256 threads (32x8).
// ---------------------------------------------------------------------------
__global__ __launch_bounds__(256) void castT_w_kernel(
    const float* __restrict__ Wq, const float* __restrict__ Wk,
    const float* __restrict__ Wv, const float* __restrict__ Wo,
    ushort_t* __restrict__ Wt_all)
{
    __shared__ float t[32][33];
    const int z = blockIdx.z;
    const float* W = (z == 0) ? Wq : (z == 1) ? Wk : (z == 2) ? Wv : Wo;
    ushort_t* Wt = Wt_all + (size_t)z * Ec * Ec;
    const int x0 = blockIdx.x * 32, y0 = blockIdx.y * 32;
    const int tx = threadIdx.x & 31, ty = threadIdx.x >> 5;   // ty 0..7
#pragma unroll
    for (int j = 0; j < 4; j++)
        t[ty + 8 * j][tx] = W[(size_t)(y0 + ty + 8 * j) * Ec + x0 + tx];
    __syncthreads();
#pragma unroll
    for (int j = 0; j < 4; j++)
        Wt[(size_t)(x0 + ty + 8 * j) * Ec + y0 + tx] = f2bf(t[tx][ty + 8 * j]);
}

// ---------------------------------------------------------------------------
// Kernel 1: fused QKV projection via bf16 MFMA.
//   C[m, n] = xb[m,:] @ W[:, n] + b,  n in [0,1152), which = n/384.
// 128x128 tile, BK=64, 256 threads = 4 waves (2x2 of 64x64 subtiles).
// LDS tiles are [row][64k] bf16 (128 B rows), XOR-swizzled at 16B-chunk
// granularity: chunk kc of row r holds global chunk (kc ^ (r&7)).  The
// global_load_lds source address applies the same XOR so the LDS dest stays
// linear (rule 21); ds_read_b128 applies the XOR on read -> 2-way conflicts
// only (free).  Output written bf16 directly in (B,H,L,D) layout, bias fused.
// ---------------------------------------------------------------------------
__global__ __launch_bounds__(256) void qkv_mfma_kernel(
    const ushort_t* __restrict__ xb, const ushort_t* __restrict__ Wt,
    const float* __restrict__ bq, const float* __restrict__ bk,
    const float* __restrict__ bv, ushort_t* __restrict__ qkv)
{
    __shared__ __align__(16) ushort_t As[128 * 64];
    __shared__ __align__(16) ushort_t Bs[128 * 64];

    const int tid = threadIdx.x;
    const int lane = tid & 63;
    const int wid = tid >> 6;
    const int wr = wid >> 1, wc = wid & 1;
    const int m0 = blockIdx.x * 128;
    const int n0 = blockIdx.y * 128;
    const int which = n0 / Ec;            // tile fully inside one matrix (384=3*128)
    const int nm0 = n0 - which * Ec;
    const ushort_t* Wmat = Wt + (size_t)which * Ec * Ec;
    const float* bias = (which == 0) ? bq : (which == 1) ? bk : bv;

    f32x4 acc[4][4];
#pragma unroll
    for (int i = 0; i < 4; i++)
#pragma unroll
        for (int j = 0; j < 4; j++) acc[i][j] = (f32x4){0.f, 0.f, 0.f, 0.f};

    for (int kt = 0; kt < Ec; kt += 64) {
#pragma unroll
        for (int c = 0; c < 4; c++) {
            int ci  = (wid * 4 + c) * 64 + lane;     // linear 16B chunk 0..1023
            int row = ci >> 3, kc = ci & 7;
            int kcs = kc ^ (row & 7);                // inverse swizzle on SOURCE
            int rowA = m0 + row; rowA = rowA < MT ? rowA : MT - 1;
            GLOAD_LDS16(xb + (size_t)rowA * Ec + kt + kcs * 8,
                        As + (size_t)(wid * 4 + c) * 512);
            GLOAD_LDS16(Wmat + (size_t)(nm0 + row) * Ec + kt + kcs * 8,
                        Bs + (size_t)(wid * 4 + c) * 512);
        }
        __syncthreads();   // compiler emits vmcnt(0) drain before barrier

#pragma unroll
        for (int ki = 0; ki < 2; ki++) {
            short8 a[4], b[4];
            const int kchunk = ki * 4 + (lane >> 4);
#pragma unroll
            for (int mi = 0; mi < 4; mi++) {
                int row = wr * 64 + mi * 16 + (lane & 15);
                a[mi] = *(const short8*)(As + row * 64 + ((kchunk ^ (row & 7)) * 8));
            }
#pragma unroll
            for (int ni = 0; ni < 4; ni++) {
                int row = wc * 64 + ni * 16 + (lane & 15);
                b[ni] = *(const short8*)(Bs + row * 64 + ((kchunk ^ (row & 7)) * 8));
            }
#pragma unroll
            for (int mi = 0; mi < 4; mi++)
#pragma unroll
                for (int ni = 0; ni < 4; ni++)
                    acc[mi][ni] = __builtin_amdgcn_mfma_f32_16x16x32_bf16(
                        a[mi], b[ni], acc[mi][ni], 0, 0, 0);
        }
        __syncthreads();
    }

    // Epilogue: C/D layout col=lane&15, row=(lane>>4)*4+r  [m89-verified]
    const int colL = lane & 15;
    const int rowL = (lane >> 4) * 4;
#pragma unroll
    for (int ni = 0; ni < 4; ni++) {
        int nm = nm0 + wc * 64 + ni * 16 + colL;    // 0..383 within matrix
        float bv_ = bias[nm];
        int h = nm >> 6, d = nm & 63;
#pragma unroll
        for (int mi = 0; mi < 4; mi++) {
#pragma unroll
            for (int r = 0; r < 4; r++) {
                int m = m0 + wr * 64 + mi * 16 + rowL + r;
                if (m < MT) {
                    int b_ = m / Lc, l = m - b_ * Lc;
                    qkv[(size_t)which * BHLD +
                        ((size_t)(b_ * Hc + h) * Lc + l) * Dc + d] =
                        f2bf(acc[mi][ni][r] + bv_);
                }
            }
        }
    }
}

// ---------------------------------------------------------------------------
// Kernel 2: CLS-token attention (bf16 Q/K/V). One block per (b,h).
// ---------------------------------------------------------------------------
__global__ __launch_bounds__(256) void cls_attn_kernel(
    const ushort_t* __restrict__ qkv, ushort_t* __restrict__ attn_rows)
{
    const int bh = blockIdx.x;  // 0..47
    const ushort_t* Q = qkv + (size_t)bh * Lc * Dc;
    const ushort_t* K = qkv + (size_t)BHLD + (size_t)bh * Lc * Dc;
    const ushort_t* V = qkv + 2 * (size_t)BHLD + (size_t)bh * Lc * Dc;

    __shared__ float qs[64];
    __shared__ float sc[Lc];
    __shared__ float red[256];

    const int tid = threadIdx.x;
    if (tid < 64) qs[tid] = bf2f(Q[tid]);
    __syncthreads();

    float lmax = -1e30f;
    for (int k = tid; k < Lc; k += 256) {
        const ushort4* kp = (const ushort4*)(K + (size_t)k * Dc);
        float s = 0.f;
#pragma unroll
        for (int c = 0; c < 16; c++) {
            ushort4 kv = kp[c];
            s += qs[c * 4 + 0] * bf2f(kv.x) + qs[c * 4 + 1] * bf2f(kv.y) +
                 qs[c * 4 + 2] * bf2f(kv.z) + qs[c * 4 + 3] * bf2f(kv.w);
        }
        s *= SCALE;
        sc[k] = s;
        lmax = fmaxf(lmax, s);
    }
    red[tid] = lmax; __syncthreads();
    for (int off = 128; off > 0; off >>= 1) {
        if (tid < off) red[tid] = fmaxf(red[tid], red[tid + off]);
        __syncthreads();
    }
    const float m = red[0];
    __syncthreads();

    float lsum = 0.f;
    for (int k = tid; k < Lc; k += 256) {
        float p = __expf(sc[k] - m);
        sc[k] = p;
        lsum += p;
    }
    red[tid] = lsum; __syncthreads();
    for (int off = 128; off > 0; off >>= 1) {
        if (tid < off) red[tid] += red[tid + off];
        __syncthreads();
    }
    const float inv = 1.f / red[0];
    __syncthreads();

    const int d = tid & 63, slice = tid >> 6;
    float acc = 0.f;
    for (int k = slice; k < Lc; k += 4) acc += sc[k] * bf2f(V[(size_t)k * Dc + d]);
    red[tid] = acc; __syncthreads();
    if (tid < 64) {
        float o = (red[tid] + red[tid + 64] + red[tid + 128] + red[tid + 192]) * inv;
        int b_ = bh / Hc, h = bh - b_ * Hc;
        attn_rows[(size_t)(b_ * Lc) * Ec + h * 64 + tid] = f2bf(o);  // l = 0 row
    }
}

// ---------------------------------------------------------------------------
// Kernel 3: windowed attention for queries l=1..1024 (bf16 Q/K/V).
// Block = 64 queries of one (b,h).  Slots w=0..32 -> key pos l+w-16
// (valid iff 1<=pos<=1024); slot 33 = CLS key (pos 0).  4 lanes/query.
// LDS rows padded to stride 68 floats (16B-aligned, conflict-light).
// ---------------------------------------------------------------------------
__global__ __launch_bounds__(256) void win_attn_kernel(
    const ushort_t* __restrict__ qkv, ushort_t* __restrict__ attn_rows)
{
    const int t = blockIdx.x;    // 0..15
    const int bh = blockIdx.y;   // 0..47
    const int l0 = 1 + t * 64;
    const ushort_t* Q = qkv + (size_t)bh * Lc * Dc;
    const ushort_t* K = qkv + (size_t)BHLD + (size_t)bh * Lc * Dc;
    const ushort_t* V = qkv + 2 * (size_t)BHLD + (size_t)bh * Lc * Dc;

    __shared__ float Kw[97][68];
    __shared__ float Vw[97][68];
    __shared__ float Qs[64][68];
    __shared__ float P[64][36];

    const int tid = threadIdx.x;
    for (int idx = tid; idx < 97 * 16; idx += 256) {
        int j = idx >> 4, c = idx & 15;
        int p = (j < 96) ? (l0 - 16 + j) : 0;
        bool valid = (j == 96) || (p >= 1 && p <= 1024);
        int pc = p < 0 ? 0 : (p > 1024 ? 1024 : p);
        ushort4 kv = ((const ushort4*)(K + (size_t)pc * Dc))[c];
        ushort4 vv = ((const ushort4*)(V + (size_t)pc * Dc))[c];
        float z = valid ? 1.f : 0.f;
        Kw[j][c * 4 + 0] = z * bf2f(kv.x); Kw[j][c * 4 + 1] = z * bf2f(kv.y);
        Kw[j][c * 4 + 2] = z * bf2f(kv.z); Kw[j][c * 4 + 3] = z * bf2f(kv.w);
        Vw[j][c * 4 + 0] = z * bf2f(vv.x); Vw[j][c * 4 + 1] = z * bf2f(vv.y);
        Vw[j][c * 4 + 2] = z * bf2f(vv.z); Vw[j][c * 4 + 3] = z * bf2f(vv.w);
    }
    for (int idx = tid; idx < 64 * 16; idx += 256) {
        int j = idx >> 4, c = idx & 15;
        ushort4 qv = ((const ushort4*)(Q + (size_t)(l0 + j) * Dc))[c];
        Qs[j][c * 4 + 0] = bf2f(qv.x); Qs[j][c * 4 + 1] = bf2f(qv.y);
        Qs[j][c * 4 + 2] = bf2f(qv.z); Qs[j][c * 4 + 3] = bf2f(qv.w);
    }
    __syncthreads();

    const int q = tid >> 2, sub = tid & 3;
    const int l = l0 + q;

    float4 qreg[16];
#pragma unroll
    for (int i = 0; i < 16; i++) qreg[i] = *(const float4*)&Qs[q][i * 4];

    float svals[9];
    float lmax = -1e30f;
    int nw = 0;
    for (int w = sub; w < 34; w += 4) {
        int j = (w < 33) ? (q + w) : 96;
        const float* kr = &Kw[j][0];
        float s = 0.f;
#pragma unroll
        for (int i = 0; i < 16; i++) {
            float4 kv = *(const float4*)(kr + i * 4);
            s += qreg[i].x * kv.x + qreg[i].y * kv.y +
                 qreg[i].z * kv.z + qreg[i].w * kv.w;
        }
        s *= SCALE;
        bool valid = (w == 33) || ((l + w - 16 >= 1) && (l + w - 16 <= 1024));
        if (!valid) s = -1e30f;
        svals[nw++] = s;
        lmax = fmaxf(lmax, s);
    }
    lmax = fmaxf(lmax, __shfl_xor(lmax, 1));
    lmax = fmaxf(lmax, __shfl_xor(lmax, 2));

    float lsum = 0.f;
    nw = 0;
    for (int w = sub; w < 34; w += 4) {
        float p = __expf(svals[nw++] - lmax);
        P[q][w] = p;
        lsum += p;
    }
    lsum += __shfl_xor(lsum, 1);
    lsum += __shfl_xor(lsum, 2);
    const float inv = 1.f / lsum;
    __syncthreads();

    float4 o4[4];
#pragma unroll
    for (int i = 0; i < 4; i++) o4[i] = make_float4(0.f, 0.f, 0.f, 0.f);
    for (int w = 0; w < 34; w++) {
        int j = (w < 33) ? (q + w) : 96;
        float p = P[q][w];
        const float* vr = &Vw[j][sub * 16];
#pragma unroll
        for (int i = 0; i < 4; i++) {
            float4 vv = *(const float4*)(vr + i * 4);
            o4[i].x += p * vv.x; o4[i].y += p * vv.y;
            o4[i].z += p * vv.z; o4[i].w += p * vv.w;
        }
    }
    int b_ = bh / Hc, h = bh - b_ * Hc;
    size_t base = (size_t)(b_ * Lc + l) * Ec + h * 64 + sub * 16;
#pragma unroll
    for (int i = 0; i < 4; i++) {
        attn_rows[base + i * 4 + 0] = f2bf(o4[i].x * inv);
        attn_rows[base + i * 4 + 1] = f2bf(o4[i].y * inv);
        attn_rows[base + i * 4 + 2] = f2bf(o4[i].z * inv);
        attn_rows[base + i * 4 + 3] = f2bf(o4[i].w * inv);
    }
}

// ---------------------------------------------------------------------------
// Kernel 4: output projection via bf16 MFMA.
//   out[m, n] = attn_rows[m,:] @ Wo[:, n] + bo[n], fp32 output.
// Same structure as qkv_mfma_kernel; N=384 -> gridDim.y = 3.
// ---------------------------------------------------------------------------
__global__ __launch_bounds__(256) void out_mfma_kernel(
    const ushort_t* __restrict__ attn_rows, const ushort_t* __restrict__ Wot,
    const float* __restrict__ bo, float* __restrict__ out)
{
    __shared__ __align__(16) ushort_t As[128 * 64];
    __shared__ __align__(16) ushort_t Bs[128 * 64];

    const int tid = threadIdx.x;
    const int lane = tid & 63;
    const int wid = tid >> 6;
    const int wr = wid >> 1, wc = wid & 1;
    const int m0 = blockIdx.x * 128;
    const int n0 = blockIdx.y * 128;

    f32x4 acc[4][4];
#pragma unroll
    for (int i = 0; i < 4; i++)
#pragma unroll
        for (int j = 0; j < 4; j++) acc[i][j] = (f32x4){0.f, 0.f, 0.f, 0.f};

    for (int kt = 0; kt < Ec; kt += 64) {
#pragma unroll
        for (int c = 0; c < 4; c++) {
            int ci  = (wid * 4 + c) * 64 + lane;
            int row = ci >> 3, kc = ci & 7;
            int kcs = kc ^ (row & 7);
            int rowA = m0 + row; rowA = rowA < MT ? rowA : MT - 1;
            GLOAD_LDS16(attn_rows + (size_t)rowA * Ec + kt + kcs * 8,
                        As + (size_t)(wid * 4 + c) * 512);
            GLOAD_LDS16(Wot + (size_t)(n0 + row) * Ec + kt + kcs * 8,
                        Bs + (size_t)(wid * 4 + c) * 512);
        }
        __syncthreads();

#pragma unroll
        for (int ki = 0; ki < 2; ki++) {
            short8 a[4], b[4];
            const int kchunk = ki * 4 + (lane >> 4);
#pragma unroll
            for (int mi = 0; mi < 4; mi++) {
                int row = wr * 64 + mi * 16 + (lane & 15);
                a[mi] = *(const short8*)(As + row * 64 + ((kchunk ^ (row & 7)) * 8));
            }
#pragma unroll
            for (int ni = 0; ni < 4; ni++) {
                int row = wc * 64 + ni * 16 + (lane & 15);
                b[ni] = *(const short8*)(Bs + row * 64 + ((kchunk ^ (row & 7)) * 8));
            }
#pragma unroll
            for (int mi = 0; mi < 4; mi++)
#pragma unroll
                for (int ni = 0; ni < 4; ni++)
                    acc[mi][ni] = __builtin_amdgcn_mfma_f32_16x16x32_bf16(
                        a[mi], b[ni], acc[mi][ni], 0, 0, 0);
        }
        __syncthreads();
    }

    const int colL = lane & 15;
    const int rowL = (lane >> 4) * 4;
#pragma unroll
    for (int ni = 0; ni < 4; ni++) {
        int n = n0 + wc * 64 + ni * 16 + colL;
        float bo_v = bo[n];
#pragma unroll
        for (int mi = 0; mi < 4; mi++) {
#pragma unroll
            for (int r = 0; r < 4; r++) {
                int m = m0 + wr * 64 + mi * 16 + rowL + r;
                if (m < MT) out[(size_t)m * Ec + n] = acc[mi][ni][r] + bo_v;
            }
        }
    }
}

// ---------------------------------------------------------------------------
extern "C" void kernel_launch(void* const* d_in, const int* in_sizes, int n_in,
                              void* d_out, int out_size, void* d_ws, size_t ws_size,
                              hipStream_t stream)
{
    const float* x  = (const float*)d_in[0];
    const float* Wq = (const float*)d_in[1];
    const float* bq = (const float*)d_in[2];
    const float* Wk = (const float*)d_in[3];
    const float* bk = (const float*)d_in[4];
    const float* Wv = (const float*)d_in[5];
    const float* bv = (const float*)d_in[6];
    const float* Wo = (const float*)d_in[7];
    const float* bo = (const float*)d_in[8];
    float* out = (float*)d_out;

    // Workspace layout (ushorts): xb | Wt(4 mats) | qkv(3x) | attn_rows  = 45.3 MB
    ushort_t* xb    = (ushort_t*)d_ws;
    ushort_t* Wt    = xb + (size_t)MT * Ec;              // 6,297,600
    ushort_t* qkvb  = Wt + (size_t)4 * Ec * Ec;          // + 589,824
    ushort_t* attnb = qkvb + (size_t)3 * BHLD;           // + 9,446,400

    cast_x_kernel<<<(MT * Ec) / 4 / 256, 256, 0, stream>>>(x, xb);
    castT_w_kernel<<<dim3(12, 12, 4), 256, 0, stream>>>(Wq, Wk, Wv, Wo, Wt);

    qkv_mfma_kernel<<<dim3((MT + 127) / 128, 9), 256, 0, stream>>>(
        xb, Wt, bq, bk, bv, qkvb);

    cls_attn_kernel<<<Bc * Hc, 256, 0, stream>>>(qkvb, attnb);
    win_attn_kernel<<<dim3(16, Bc * Hc), 256, 0, stream>>>(qkvb, attnb);

    out_mfma_kernel<<<dim3((MT + 127) / 128, 3), 256, 0, stream>>>(
        attnb, Wt + (size_t)3 * Ec * Ec, bo, out);
}

// Round 3
// 175.506 us; speedup vs baseline: 2.4916x; 1.3032x over previous
//
#include <hip/hip_runtime.h>
#include <hip/hip_bf16.h>

typedef unsigned short ushort_t;
typedef __attribute__((ext_vector_type(8))) short short8;
typedef __attribute__((ext_vector_type(4))) float f32x4;

// Problem constants (B=8, L=1025, E=384, H=6, D=64, WIN=33, PAD=16)
constexpr int Bc = 8;
constexpr int Lc = 1025;
constexpr int Ec = 384;
constexpr int Hc = 6;
constexpr int Dc = 64;
constexpr int MT = Bc * Lc;              // 8200 rows
constexpr int BHLD = Bc * Hc * Lc * Dc;  // 3,148,800 elems per tensor
constexpr int LT = 1032;                 // padded v_t row stride (16B-aligned rows)
constexpr float SCALE = 0.125f;          // 1/sqrt(64)
constexpr int NCH = 5;                   // cls split-K chunks of 256 keys

__device__ __forceinline__ float bf2f(ushort_t u) {
    union { unsigned int u; float f; } v; v.u = ((unsigned int)u) << 16; return v.f;
}
__device__ __forceinline__ ushort_t f2bf(float f) {
    union { float f; unsigned int u; } v; v.f = f;
    unsigned int r = v.u + 0x7FFFu + ((v.u >> 16) & 1u);
    return (ushort_t)(r >> 16);
}

#define GLOAD_LDS16(gp, lp)                                                          \
    __builtin_amdgcn_global_load_lds(                                                \
        (const __attribute__((address_space(1))) unsigned int*)(gp),                 \
        (__attribute__((address_space(3))) unsigned int*)(lp), 16, 0, 0)

// ---------------------------------------------------------------------------
// Cast x (fp32) -> xb (bf16).
// ---------------------------------------------------------------------------
__global__ __launch_bounds__(256) void cast_x_kernel(
    const float* __restrict__ x, ushort_t* __restrict__ xb)
{
    int i = blockIdx.x * 256 + threadIdx.x;   // exactly 3075 blocks
    float4 v = ((const float4*)x)[i];
    ushort4 o;
    o.x = f2bf(v.x); o.y = f2bf(v.y); o.z = f2bf(v.z); o.w = f2bf(v.w);
    ((ushort4*)xb)[i] = o;
}

// ---------------------------------------------------------------------------
// Transpose+cast weights: Wt[z][n][k] = W_z[k][n] bf16.  z: 0=Wq 1=Wk 2=Wv 3=Wo
// ---------------------------------------------------------------------------
__global__ __launch_bounds__(256) void castT_w_kernel(
    const float* __restrict__ Wq, const float* __restrict__ Wk,
    const float* __restrict__ Wv, const float* __restrict__ Wo,
    ushort_t* __restrict__ Wt_all)
{
    __shared__ float t[32][33];
    const int z = blockIdx.z;
    const float* W = (z == 0) ? Wq : (z == 1) ? Wk : (z == 2) ? Wv : Wo;
    ushort_t* Wt = Wt_all + (size_t)z * Ec * Ec;
    const int x0 = blockIdx.x * 32, y0 = blockIdx.y * 32;
    const int tx = threadIdx.x & 31, ty = threadIdx.x >> 5;
#pragma unroll
    for (int j = 0; j < 4; j++)
        t[ty + 8 * j][tx] = W[(size_t)(y0 + ty + 8 * j) * Ec + x0 + tx];
    __syncthreads();
#pragma unroll
    for (int j = 0; j < 4; j++)
        Wt[(size_t)(x0 + ty + 8 * j) * Ec + y0 + tx] = f2bf(t[tx][ty + 8 * j]);
}

// ---------------------------------------------------------------------------
// Kernel 1: fused QKV projection via bf16 MFMA (128x128 tile, BK=64, 4 waves).
// ---------------------------------------------------------------------------
__global__ __launch_bounds__(256) void qkv_mfma_kernel(
    const ushort_t* __restrict__ xb, const ushort_t* __restrict__ Wt,
    const float* __restrict__ bq, const float* __restrict__ bk,
    const float* __restrict__ bv, ushort_t* __restrict__ qkv)
{
    __shared__ __align__(16) ushort_t As[128 * 64];
    __shared__ __align__(16) ushort_t Bs[128 * 64];

    const int tid = threadIdx.x;
    const int lane = tid & 63;
    const int wid = tid >> 6;
    const int wr = wid >> 1, wc = wid & 1;
    const int m0 = blockIdx.x * 128;
    const int n0 = blockIdx.y * 128;
    const int which = n0 / Ec;
    const int nm0 = n0 - which * Ec;
    const ushort_t* Wmat = Wt + (size_t)which * Ec * Ec;
    const float* bias = (which == 0) ? bq : (which == 1) ? bk : bv;

    f32x4 acc[4][4];
#pragma unroll
    for (int i = 0; i < 4; i++)
#pragma unroll
        for (int j = 0; j < 4; j++) acc[i][j] = (f32x4){0.f, 0.f, 0.f, 0.f};

    for (int kt = 0; kt < Ec; kt += 64) {
#pragma unroll
        for (int c = 0; c < 4; c++) {
            int ci  = (wid * 4 + c) * 64 + lane;
            int row = ci >> 3, kc = ci & 7;
            int kcs = kc ^ (row & 7);
            int rowA = m0 + row; rowA = rowA < MT ? rowA : MT - 1;
            GLOAD_LDS16(xb + (size_t)rowA * Ec + kt + kcs * 8,
                        As + (size_t)(wid * 4 + c) * 512);
            GLOAD_LDS16(Wmat + (size_t)(nm0 + row) * Ec + kt + kcs * 8,
                        Bs + (size_t)(wid * 4 + c) * 512);
        }
        __syncthreads();

#pragma unroll
        for (int ki = 0; ki < 2; ki++) {
            short8 a[4], b[4];
            const int kchunk = ki * 4 + (lane >> 4);
#pragma unroll
            for (int mi = 0; mi < 4; mi++) {
                int row = wr * 64 + mi * 16 + (lane & 15);
                a[mi] = *(const short8*)(As + row * 64 + ((kchunk ^ (row & 7)) * 8));
            }
#pragma unroll
            for (int ni = 0; ni < 4; ni++) {
                int row = wc * 64 + ni * 16 + (lane & 15);
                b[ni] = *(const short8*)(Bs + row * 64 + ((kchunk ^ (row & 7)) * 8));
            }
#pragma unroll
            for (int mi = 0; mi < 4; mi++)
#pragma unroll
                for (int ni = 0; ni < 4; ni++)
                    acc[mi][ni] = __builtin_amdgcn_mfma_f32_16x16x32_bf16(
                        a[mi], b[ni], acc[mi][ni], 0, 0, 0);
        }
        __syncthreads();
    }

    const int colL = lane & 15;
    const int rowL = (lane >> 4) * 4;
#pragma unroll
    for (int ni = 0; ni < 4; ni++) {
        int nm = nm0 + wc * 64 + ni * 16 + colL;
        float bv_ = bias[nm];
        int h = nm >> 6, d = nm & 63;
#pragma unroll
        for (int mi = 0; mi < 4; mi++) {
#pragma unroll
            for (int r = 0; r < 4; r++) {
                int m = m0 + wr * 64 + mi * 16 + rowL + r;
                if (m < MT) {
                    int b_ = m / Lc, l = m - b_ * Lc;
                    qkv[(size_t)which * BHLD +
                        ((size_t)(b_ * Hc + h) * Lc + l) * Dc + d] =
                        f2bf(acc[mi][ni][r] + bv_);
                }
            }
        }
    }
}

// ---------------------------------------------------------------------------
// Kernel 2: V transpose (B,H,L,D) -> (B,H,D,Lpad) bf16, for PV B-operand.
// ---------------------------------------------------------------------------
__global__ __launch_bounds__(256) void vT_kernel(
    const ushort_t* __restrict__ qkv, ushort_t* __restrict__ vt)
{
    __shared__ ushort_t t[64][68];
    const int bh = blockIdx.y;
    const int l0 = blockIdx.x * 64;        // gridDim.x = 17
    const ushort_t* V = qkv + 2 * (size_t)BHLD + (size_t)bh * Lc * Dc;
    ushort_t* vto = vt + (size_t)bh * 64 * LT;
    const int tid = threadIdx.x;
#pragma unroll
    for (int i = 0; i < 4; i++) {
        int idx = tid + i * 256;           // ushort4 position in tile
        int l = idx >> 4, dc = idx & 15;
        int ls = l0 + l; ls = ls > 1024 ? 1024 : ls;
        ushort4 v = *(const ushort4*)(V + (size_t)ls * Dc + dc * 4);
        *(ushort4*)&t[l][dc * 4] = v;
    }
    __syncthreads();
#pragma unroll
    for (int i = 0; i < 4; i++) {
        int idx = tid + i * 256;
        int d = idx >> 4, lc = idx & 15;
        ushort4 o;
        o.x = t[lc * 4 + 0][d]; o.y = t[lc * 4 + 1][d];
        o.z = t[lc * 4 + 2][d]; o.w = t[lc * 4 + 3][d];
        int lw = l0 + lc * 4;
        if (lw <= 1024)                    // writes up to l=1027 < LT pad: safe
            *(ushort4*)(vto + (size_t)d * LT + lw) = o;
    }
}

// ---------------------------------------------------------------------------
// Kernel 3a: CLS attention, split-K partials. grid (48, NCH), 256 threads.
// Chunk ch covers keys [ch*256, min(1025, ch*256+256)).
// Writes per (bh,ch): [m, sum, o[64]] floats (o unnormalized).
// ---------------------------------------------------------------------------
__global__ __launch_bounds__(256) void cls_part_kernel(
    const ushort_t* __restrict__ qkv, float* __restrict__ part)
{
    const int bh = blockIdx.x, ch = blockIdx.y;
    const int base = ch * 256;
    const int count = min(256, Lc - base);
    const ushort_t* Q = qkv + (size_t)bh * Lc * Dc;
    const ushort_t* K = Q + (size_t)BHLD;
    const ushort_t* V = Q + 2 * (size_t)BHLD;

    __shared__ float qs[64];
    __shared__ float ps[256];
    __shared__ float red[256];

    const int tid = threadIdx.x;
    if (tid < 64) qs[tid] = bf2f(Q[tid]);
    __syncthreads();

    float s = -1e30f;
    if (tid < count) {
        const ushort4* kp = (const ushort4*)(K + (size_t)(base + tid) * Dc);
        float acc = 0.f;
#pragma unroll
        for (int c = 0; c < 16; c++) {
            ushort4 kv = kp[c];
            acc += qs[c * 4 + 0] * bf2f(kv.x) + qs[c * 4 + 1] * bf2f(kv.y) +
                   qs[c * 4 + 2] * bf2f(kv.z) + qs[c * 4 + 3] * bf2f(kv.w);
        }
        s = acc * SCALE;
    }
    red[tid] = s; __syncthreads();
    for (int off = 128; off > 0; off >>= 1) {
        if (tid < off) red[tid] = fmaxf(red[tid], red[tid + off]);
        __syncthreads();
    }
    const float m = red[0];
    __syncthreads();

    float p = (tid < count) ? __expf(s - m) : 0.f;
    ps[tid] = p;
    red[tid] = p; __syncthreads();
    for (int off = 128; off > 0; off >>= 1) {
        if (tid < off) red[tid] += red[tid + off];
        __syncthreads();
    }
    const float S = red[0];
    __syncthreads();

    const int d = tid & 63, sl = tid >> 6;
    float acc = 0.f;
    for (int i = sl; i < count; i += 4)
        acc += ps[i] * bf2f(V[(size_t)(base + i) * Dc + d]);
    red[tid] = acc; __syncthreads();
    if (tid < 64) {
        float o = red[tid] + red[tid + 64] + red[tid + 128] + red[tid + 192];
        float* pp = part + (size_t)(bh * NCH + ch) * 66;
        pp[2 + tid] = o;
        if (tid == 0) { pp[0] = m; pp[1] = S; }
    }
}

// ---------------------------------------------------------------------------
// Kernel 3b: CLS combine. grid 48, 64 threads.
// ---------------------------------------------------------------------------
__global__ __launch_bounds__(64) void cls_comb_kernel(
    const float* __restrict__ part, ushort_t* __restrict__ attnb)
{
    const int bh = blockIdx.x, d = threadIdx.x;
    float M = -1e30f;
#pragma unroll
    for (int ch = 0; ch < NCH; ch++)
        M = fmaxf(M, part[(size_t)(bh * NCH + ch) * 66]);
    float S = 0.f, O = 0.f;
#pragma unroll
    for (int ch = 0; ch < NCH; ch++) {
        const float* pp = part + (size_t)(bh * NCH + ch) * 66;
        float w = __expf(pp[0] - M);
        S += pp[1] * w;
        O += pp[2 + d] * w;
    }
    const int b_ = bh / Hc, h = bh - b_ * Hc;
    attnb[(size_t)(b_ * Lc) * Ec + h * 64 + d] = f2bf(O / S);   // row l=0
}

// ---------------------------------------------------------------------------
// Kernel 4: windowed attention via MFMA. grid (16, 48), 256 threads (4 waves).
// Block t: queries l = l0..l0+63, l0 = 1+64t.  Key slots j=0..127 map to
// kpos = k0 + j (k0 = l0-17); CLS at slot 112.  Band: valid j in [q+1, q+33]
// with 1 <= kpos <= 1024, or j==112.
// LDS: Kb[128][64] bf16 (chunk-xor j&7), Vb[64][128] (chunk-xor d&15, from
// transposed v_t), QP union: Q[64][64] then P[64][128] (chunk-xor q&15).
// ---------------------------------------------------------------------------
__global__ __launch_bounds__(256) void win_mfma_kernel(
    const ushort_t* __restrict__ qkv, const ushort_t* __restrict__ vt,
    ushort_t* __restrict__ attnb)
{
    __shared__ __align__(16) ushort_t Kb[128 * 64];
    __shared__ __align__(16) ushort_t Vb[64 * 128];
    __shared__ __align__(16) ushort_t QP[64 * 128];   // Q (8KB) then P (16KB)

    const int t = blockIdx.x, bh = blockIdx.y;
    const int l0 = 1 + t * 64, k0 = l0 - 17;          // k0 = 64t-16, mult of 8
    const int tid = threadIdx.x, lane = tid & 63, wid = tid >> 6;
    const ushort_t* Qg = qkv + (size_t)bh * Lc * Dc;
    const ushort_t* Kg = Qg + (size_t)BHLD;
    const ushort_t* Vt = vt + (size_t)bh * 64 * LT;

    // ---- stage K (4 gloads), V (4), Q (2) ----
#pragma unroll
    for (int i = 0; i < 4; i++) {
        int p = (i * 4 + wid) * 64 + lane;
        {   // K: row j (one kpos per row), 8 chunks of 16B
            int j = p >> 3, c = p & 7, g = c ^ (j & 7);
            int kp = (j <= 111) ? min(max(k0 + j, 0), 1024) : 0;  // j>=112: CLS/masked
            GLOAD_LDS16(Kg + (size_t)kp * Dc + g * 8,
                        Kb + (size_t)(i * 4 + wid) * 512);
        }
        {   // V^T: row d, 16 chunks of 8 kpos; g==14 -> CLS chunk (kpos 0..7)
            int d = p >> 4, jc = p & 15, g = jc ^ (d & 15);
            int kb = (g <= 13) ? max(k0 + g * 8, 0) : 0;  // over-read into pad OK (masked)
            GLOAD_LDS16(Vt + (size_t)d * LT + kb,
                        Vb + (size_t)(i * 4 + wid) * 512);
        }
    }
#pragma unroll
    for (int i = 0; i < 2; i++) {
        int p = (i * 4 + wid) * 64 + lane;
        int q = p >> 3, c = p & 7, g = c ^ (q & 7);
        GLOAD_LDS16(Qg + (size_t)(l0 + q) * Dc + g * 8,
                    QP + (size_t)(i * 4 + wid) * 512);
    }
    __syncthreads();

    // ---- QK^T: wave owns q-tile wid (16 rows) x 8 j-tiles ----
    f32x4 sacc[8];
#pragma unroll
    for (int tj = 0; tj < 8; tj++) sacc[tj] = (f32x4){0.f, 0.f, 0.f, 0.f};
#pragma unroll
    for (int ki = 0; ki < 2; ki++) {
        const int gc = ki * 4 + (lane >> 4);
        const int qrow = wid * 16 + (lane & 15);
        short8 a = *(const short8*)(QP + qrow * 64 + ((gc ^ (qrow & 7)) * 8));
#pragma unroll
        for (int tj = 0; tj < 8; tj++) {
            int jrow = tj * 16 + (lane & 15);
            short8 b = *(const short8*)(Kb + jrow * 64 + ((gc ^ (jrow & 7)) * 8));
            sacc[tj] = __builtin_amdgcn_mfma_f32_16x16x32_bf16(a, b, sacc[tj], 0, 0, 0);
        }
    }
    __syncthreads();   // Q region dead; P may now overwrite it

    // ---- softmax (rows q = wid*16 + (lane>>4)*4 + r), write P to LDS ----
    const int qb = wid * 16 + (lane >> 4) * 4;
    const int cl = lane & 15;
    float inv[4];
#pragma unroll
    for (int r = 0; r < 4; r++) {
        const int q = qb + r;
        float sv[8];
        float mx = -1e30f;
#pragma unroll
        for (int tj = 0; tj < 8; tj++) {
            int j = tj * 16 + cl;
            int kp = k0 + j;
            bool valid = (j == 112) ||
                         ((j >= q + 1) && (j <= q + 33) && (kp >= 1) && (kp <= 1024));
            float s = valid ? sacc[tj][r] * SCALE : -1e30f;
            sv[tj] = s;
            mx = fmaxf(mx, s);
        }
        mx = fmaxf(mx, __shfl_xor(mx, 1));
        mx = fmaxf(mx, __shfl_xor(mx, 2));
        mx = fmaxf(mx, __shfl_xor(mx, 4));
        mx = fmaxf(mx, __shfl_xor(mx, 8));
        float sum = 0.f;
#pragma unroll
        for (int tj = 0; tj < 8; tj++) {
            float pv = __expf(sv[tj] - mx);
            sv[tj] = pv;
            sum += pv;
        }
        sum += __shfl_xor(sum, 1);
        sum += __shfl_xor(sum, 2);
        sum += __shfl_xor(sum, 4);
        sum += __shfl_xor(sum, 8);
        inv[r] = 1.f / sum;
#pragma unroll
        for (int tj = 0; tj < 8; tj++) {
            int j = tj * 16 + cl;
            QP[q * 128 + (((j >> 3) ^ (q & 15)) * 8) + (j & 7)] = f2bf(sv[tj]);
        }
    }
    __syncthreads();   // P complete

    // ---- PV: O(16x64) per wave = 4 k-steps x 4 d-tiles ----
    f32x4 oacc[4];
#pragma unroll
    for (int dt = 0; dt < 4; dt++) oacc[dt] = (f32x4){0.f, 0.f, 0.f, 0.f};
#pragma unroll
    for (int kc = 0; kc < 4; kc++) {
        const int gc = kc * 4 + (lane >> 4);
        const int qrow = wid * 16 + (lane & 15);
        short8 pa = *(const short8*)(QP + qrow * 128 + ((gc ^ (qrow & 15)) * 8));
#pragma unroll
        for (int dt = 0; dt < 4; dt++) {
            int drow = dt * 16 + (lane & 15);
            short8 vb = *(const short8*)(Vb + drow * 128 + ((gc ^ (drow & 15)) * 8));
            oacc[dt] = __builtin_amdgcn_mfma_f32_16x16x32_bf16(pa, vb, oacc[dt], 0, 0, 0);
        }
    }

    // ---- epilogue ----
    const int b_ = bh / Hc, h = bh - b_ * Hc;
#pragma unroll
    for (int dt = 0; dt < 4; dt++) {
        int d = dt * 16 + cl;
#pragma unroll
        for (int r = 0; r < 4; r++) {
            int l = l0 + qb + r;
            attnb[(size_t)(b_ * Lc + l) * Ec + h * 64 + d] = f2bf(oacc[dt][r] * inv[r]);
        }
    }
}

// ---------------------------------------------------------------------------
// Kernel 5: output projection via bf16 MFMA (fp32 out).
// ---------------------------------------------------------------------------
__global__ __launch_bounds__(256) void out_mfma_kernel(
    const ushort_t* __restrict__ attn_rows, const ushort_t* __restrict__ Wot,
    const float* __restrict__ bo, float* __restrict__ out)
{
    __shared__ __align__(16) ushort_t As[128 * 64];
    __shared__ __align__(16) ushort_t Bs[128 * 64];

    const int tid = threadIdx.x;
    const int lane = tid & 63;
    const int wid = tid >> 6;
    const int wr = wid >> 1, wc = wid & 1;
    const int m0 = blockIdx.x * 128;
    const int n0 = blockIdx.y * 128;

    f32x4 acc[4][4];
#pragma unroll
    for (int i = 0; i < 4; i++)
#pragma unroll
        for (int j = 0; j < 4; j++) acc[i][j] = (f32x4){0.f, 0.f, 0.f, 0.f};

    for (int kt = 0; kt < Ec; kt += 64) {
#pragma unroll
        for (int c = 0; c < 4; c++) {
            int ci  = (wid * 4 + c) * 64 + lane;
            int row = ci >> 3, kc = ci & 7;
            int kcs = kc ^ (row & 7);
            int rowA = m0 + row; rowA = rowA < MT ? rowA : MT - 1;
            GLOAD_LDS16(attn_rows + (size_t)rowA * Ec + kt + kcs * 8,
                        As + (size_t)(wid * 4 + c) * 512);
            GLOAD_LDS16(Wot + (size_t)(n0 + row) * Ec + kt + kcs * 8,
                        Bs + (size_t)(wid * 4 + c) * 512);
        }
        __syncthreads();

#pragma unroll
        for (int ki = 0; ki < 2; ki++) {
            short8 a[4], b[4];
            const int kchunk = ki * 4 + (lane >> 4);
#pragma unroll
            for (int mi = 0; mi < 4; mi++) {
                int row = wr * 64 + mi * 16 + (lane & 15);
                a[mi] = *(const short8*)(As + row * 64 + ((kchunk ^ (row & 7)) * 8));
            }
#pragma unroll
            for (int ni = 0; ni < 4; ni++) {
                int row = wc * 64 + ni * 16 + (lane & 15);
                b[ni] = *(const short8*)(Bs + row * 64 + ((kchunk ^ (row & 7)) * 8));
            }
#pragma unroll
            for (int mi = 0; mi < 4; mi++)
#pragma unroll
                for (int ni = 0; ni < 4; ni++)
                    acc[mi][ni] = __builtin_amdgcn_mfma_f32_16x16x32_bf16(
                        a[mi], b[ni], acc[mi][ni], 0, 0, 0);
        }
        __syncthreads();
    }

    const int colL = lane & 15;
    const int rowL = (lane >> 4) * 4;
#pragma unroll
    for (int ni = 0; ni < 4; ni++) {
        int n = n0 + wc * 64 + ni * 16 + colL;
        float bo_v = bo[n];
#pragma unroll
        for (int mi = 0; mi < 4; mi++) {
#pragma unroll
            for (int r = 0; r < 4; r++) {
                int m = m0 + wr * 64 + mi * 16 + rowL + r;
                if (m < MT) out[(size_t)m * Ec + n] = acc[mi][ni][r] + bo_v;
            }
        }
    }
}

// ---------------------------------------------------------------------------
extern "C" void kernel_launch(void* const* d_in, const int* in_sizes, int n_in,
                              void* d_out, int out_size, void* d_ws, size_t ws_size,
                              hipStream_t stream)
{
    const float* x  = (const float*)d_in[0];
    const float* Wq = (const float*)d_in[1];
    const float* bq = (const float*)d_in[2];
    const float* Wk = (const float*)d_in[3];
    const float* bk = (const float*)d_in[4];
    const float* Wv = (const float*)d_in[5];
    const float* bv = (const float*)d_in[6];
    const float* Wo = (const float*)d_in[7];
    const float* bo = (const float*)d_in[8];
    float* out = (float*)d_out;

    // ws layout (ushort units, all 16B-aligned):
    // xb | Wt(4) | qkv(3) | v_t | attnb | cls_part(float)  ~= 39.1 MB
    ushort_t* xb    = (ushort_t*)d_ws;
    ushort_t* Wt    = xb + (size_t)MT * Ec;                  // 3,148,800
    ushort_t* qkvb  = Wt + (size_t)4 * Ec * Ec;              // + 589,824
    ushort_t* vtb   = qkvb + (size_t)3 * BHLD;               // + 9,446,400
    ushort_t* attnb = vtb + (size_t)Bc * Hc * 64 * LT;       // + 3,170,304
    float* clsp     = (float*)(attnb + (size_t)MT * Ec);     // + 3,148,800

    cast_x_kernel<<<(MT * Ec) / 4 / 256, 256, 0, stream>>>(x, xb);
    castT_w_kernel<<<dim3(12, 12, 4), 256, 0, stream>>>(Wq, Wk, Wv, Wo, Wt);

    qkv_mfma_kernel<<<dim3((MT + 127) / 128, 9), 256, 0, stream>>>(
        xb, Wt, bq, bk, bv, qkvb);

    vT_kernel<<<dim3(17, Bc * Hc), 256, 0, stream>>>(qkvb, vtb);

    cls_part_kernel<<<dim3(Bc * Hc, NCH), 256, 0, stream>>>(qkvb, clsp);
    cls_comb_kernel<<<Bc * Hc, 64, 0, stream>>>(clsp, attnb);

    win_mfma_kernel<<<dim3(16, Bc * Hc), 256, 0, stream>>>(qkvb, vtb, attnb);

    out_mfma_kernel<<<dim3((MT + 127) / 128, 3), 256, 0, stream>>>(
        attnb, Wt + (size_t)3 * Ec * Ec, bo, out);
}